// Round 10
// baseline (870.164 us; speedup 1.0000x reference)
//
#include <hip/hip_runtime.h>
#include <stddef.h>

static constexpr int Nn    = 100000;   // nodes
static constexpr int Ee    = 1600000;  // edges
static constexpr int Ff    = 128;      // input features
static constexpr int Cc    = 64;       // hidden channels
static constexpr int NHh   = 256;      // nhid
static constexpr int NOUTt = 128;      // nout
static constexpr int Ll    = 4;        // hidden GCN layers
static constexpr int Gg    = 512;      // graphs

static constexpr int SCAN_BLK = 1024;
static constexpr int NBLK_SCAN = (Nn + SCAN_BLK - 1) / SCAN_BLK;   // 98

// sub-bucket = 512 contiguous nodes (dst>>9); one block owns one sub-bucket's
// csr segment -> all its dirty lines live in ONE L2 and flush once. (R8)
static constexpr int NSUB   = (Nn + 511) / 512;   // 196
static constexpr int SUBCAP = 10240;

// ---------------- pass 1: bin edges by dst>>9 into 196 sub-buckets ----------------
__global__ __launch_bounds__(256) void bin_kernel(const int* __restrict__ src,
                                                  const int* __restrict__ dst,
                                                  int* __restrict__ sb,
                                                  int* __restrict__ scnt, int E) {
    __shared__ int lcnt[NSUB], lbase[NSUB];
    const int tid = threadIdx.x;
    for (int i = tid; i < NSUB; i += 256) lcnt[i] = 0;
    __syncthreads();
    const int base = blockIdx.x * 2048;
    int pk[8], ps[8], lr[8];
    #pragma unroll
    for (int i = 0; i < 8; ++i) {
        int e = base + i * 256 + tid;
        if (e < E) {
            int d = dst[e], s = src[e];
            int sub = d >> 9;
            ps[i] = sub;
            pk[i] = s | ((d & 511) << 17);
            lr[i] = atomicAdd(&lcnt[sub], 1);
        } else ps[i] = -1;
    }
    __syncthreads();
    for (int i = tid; i < NSUB; i += 256) lbase[i] = atomicAdd(&scnt[i], lcnt[i]);
    __syncthreads();
    #pragma unroll
    for (int i = 0; i < 8; ++i) {
        if (ps[i] >= 0) {
            int pos = lbase[ps[i]] + lr[i];
            if (pos < SUBCAP) sb[(size_t)ps[i] * SUBCAP + pos] = pk[i];
        }
    }
}

// ---------------- pass 2a: per-node degree (one block per sub-bucket) ----------------
__global__ __launch_bounds__(512) void cnt3_kernel(const int* __restrict__ sb,
                                                   const int* __restrict__ scnt,
                                                   int* __restrict__ cnt) {
    __shared__ int lcnt[512];
    const int sub = blockIdx.x, tid = threadIdx.x;
    lcnt[tid] = 0;
    __syncthreads();
    const int n = scnt[sub];
    const int* bp = sb + (size_t)sub * SUBCAP;
    for (int i = tid; i < n; i += 512) atomicAdd(&lcnt[(bp[i] >> 17) & 511], 1);
    __syncthreads();
    int node = sub * 512 + tid;
    if (node < Nn) cnt[node] = lcnt[tid];
}

__global__ void dinv_kernel(const int* __restrict__ cnt, float* __restrict__ dinv, int n) {
    int i = blockIdx.x * blockDim.x + threadIdx.x;
    if (i < n) dinv[i] = rsqrtf((float)cnt[i] + 1.0f);   // + self loop
}

// ---------------- scans ----------------
__global__ __launch_bounds__(SCAN_BLK) void scan1_kernel(const int* __restrict__ cnt,
                                                         int* __restrict__ row_off,
                                                         int* __restrict__ bsum, int n) {
    __shared__ int sd[SCAN_BLK];
    int tid = threadIdx.x;
    int gid = blockIdx.x * SCAN_BLK + tid;
    int v = (gid < n) ? cnt[gid] : 0;
    sd[tid] = v;
    __syncthreads();
    #pragma unroll
    for (int off = 1; off < SCAN_BLK; off <<= 1) {
        int t = (tid >= off) ? sd[tid - off] : 0;
        __syncthreads();
        sd[tid] += t;
        __syncthreads();
    }
    if (gid < n) row_off[gid + 1] = sd[tid];
    if (tid == SCAN_BLK - 1) bsum[blockIdx.x] = sd[tid];
}

__global__ __launch_bounds__(128) void scan2_kernel(const int* __restrict__ bsum,
                                                    int* __restrict__ boff, int nb) {
    __shared__ int sd[128];
    int tid = threadIdx.x;
    sd[tid] = (tid < nb) ? bsum[tid] : 0;
    __syncthreads();
    #pragma unroll
    for (int off = 1; off < 128; off <<= 1) {
        int t = (tid >= off) ? sd[tid - off] : 0;
        __syncthreads();
        sd[tid] += t;
        __syncthreads();
    }
    if (tid < nb) boff[tid] = (tid == 0) ? 0 : sd[tid - 1];
}

__global__ void scan3_kernel(int* __restrict__ row_off, const int* __restrict__ boff, int n) {
    int gid = blockIdx.x * blockDim.x + threadIdx.x;
    if (gid < n) row_off[gid + 1] += boff[gid >> 10];
    if (gid == 0) row_off[0] = 0;
}

// ---------------- pass 2b: fill csr (one block per sub-bucket) ----------------
__global__ __launch_bounds__(512) void fill3_kernel(const int* __restrict__ sb,
                                                    const int* __restrict__ scnt,
                                                    const int* __restrict__ roff,
                                                    int* __restrict__ csr) {
    __shared__ int lcnt[512], lofs[512];
    __shared__ int gbase;
    const int sub = blockIdx.x, tid = threadIdx.x;
    lcnt[tid] = 0;
    if (tid == 0) gbase = roff[sub * 512];
    __syncthreads();
    const int n = scnt[sub];
    const int* bp = sb + (size_t)sub * SUBCAP;
    for (int i = tid; i < n; i += 512) atomicAdd(&lcnt[(bp[i] >> 17) & 511], 1);
    __syncthreads();
    int v = lcnt[tid];
    lofs[tid] = v;
    __syncthreads();
    #pragma unroll
    for (int off = 1; off < 512; off <<= 1) {
        int t = (tid >= off) ? lofs[tid - off] : 0;
        __syncthreads();
        lofs[tid] += t;
        __syncthreads();
    }
    int excl = lofs[tid] - v;
    __syncthreads();
    lcnt[tid] = excl;
    __syncthreads();
    for (int i = tid; i < n; i += 512) {
        int e = bp[i];
        int pos = atomicAdd(&lcnt[(e >> 17) & 511], 1);
        csr[gbase + pos] = e & 0x1FFFF;
    }
}

// ---------------- GEMM (layer 0 only): Y = dinv * (X @ W0) ----------------
template<int CIN>
__global__ __launch_bounds__(256) void gemm_xw(const float* __restrict__ X,
                                               const float* __restrict__ W,
                                               const float* __restrict__ dinv,
                                               float* __restrict__ Y, int n) {
    __shared__ float hs[64][68];
    __shared__ float ws[64][64];
    const int tid = threadIdx.x;
    const int tx  = tid & 15;
    const int ty  = tid >> 4;
    const int rowbase = blockIdx.x * 64;

    float acc[4][4] = {};

    for (int k0 = 0; k0 < CIN; k0 += 64) {
        #pragma unroll
        for (int i = 0; i < 4; ++i) {
            int r = ty + i * 16;
            int gr = rowbase + r;
            float4 v = make_float4(0.f, 0.f, 0.f, 0.f);
            if (gr < n) v = *(const float4*)(X + (size_t)gr * CIN + k0 + tx * 4);
            *(float4*)&hs[r][tx * 4] = v;
        }
        #pragma unroll
        for (int i = 0; i < 4; ++i) {
            int k = ty + i * 16;
            *(float4*)&ws[k][tx * 4] = *(const float4*)(W + (size_t)(k0 + k) * 64 + tx * 4);
        }
        __syncthreads();

        #pragma unroll 4
        for (int k = 0; k < 64; ++k) {
            float4 w = *(const float4*)&ws[k][tx * 4];
            float h0 = hs[ty * 4 + 0][k];
            float h1 = hs[ty * 4 + 1][k];
            float h2 = hs[ty * 4 + 2][k];
            float h3 = hs[ty * 4 + 3][k];
            acc[0][0] += h0 * w.x; acc[0][1] += h0 * w.y; acc[0][2] += h0 * w.z; acc[0][3] += h0 * w.w;
            acc[1][0] += h1 * w.x; acc[1][1] += h1 * w.y; acc[1][2] += h1 * w.z; acc[1][3] += h1 * w.w;
            acc[2][0] += h2 * w.x; acc[2][1] += h2 * w.y; acc[2][2] += h2 * w.z; acc[2][3] += h2 * w.w;
            acc[3][0] += h3 * w.x; acc[3][1] += h3 * w.y; acc[3][2] += h3 * w.z; acc[3][3] += h3 * w.w;
        }
        __syncthreads();
    }

    #pragma unroll
    for (int i = 0; i < 4; ++i) {
        int gr = rowbase + ty * 4 + i;
        if (gr < n) {
            float di = dinv[gr];
            float4 v = make_float4(acc[i][0] * di, acc[i][1] * di, acc[i][2] * di, acc[i][3] * di);
            *(float4*)(Y + (size_t)gr * 64 + tx * 4) = v;
        }
    }
}

// ---------------- layer-0 gather: t' -> u1 = dinv * relu(...) ----------------
__global__ __launch_bounds__(256) void gather_agg(const int* __restrict__ row_off,
                                                  const int* __restrict__ csr_src,
                                                  const float* __restrict__ dinv,
                                                  const float* __restrict__ t,
                                                  const float* __restrict__ b,
                                                  float* __restrict__ out, int n) {
    const int lane = threadIdx.x & 63;
    const int node = (blockIdx.x * blockDim.x + threadIdx.x) >> 6;
    if (node >= n) return;
    const int sub = lane >> 4;
    const int c4  = lane & 15;

    const int base = row_off[node];
    const int end  = row_off[node + 1];

    float4 acc = make_float4(0.f, 0.f, 0.f, 0.f);

    for (int k0 = base; k0 < end; k0 += 64) {
        int myidx = (k0 + lane < end) ? csr_src[k0 + lane] : 0;
        int nk = min(64, end - k0);
        int k = 0;
        for (; k + 8 <= nk; k += 8) {
            int s0 = __shfl(myidx, k + sub);
            int s1 = __shfl(myidx, k + 4 + sub);
            float4 v0 = *(const float4*)(t + (size_t)s0 * 64 + c4 * 4);
            float4 v1 = *(const float4*)(t + (size_t)s1 * 64 + c4 * 4);
            acc.x += v0.x; acc.y += v0.y; acc.z += v0.z; acc.w += v0.w;
            acc.x += v1.x; acc.y += v1.y; acc.z += v1.z; acc.w += v1.w;
        }
        for (; k < nk; k += 4) {
            int kk = k + sub;
            int s = __shfl(myidx, kk);
            if (kk < nk) {
                float4 v = *(const float4*)(t + (size_t)s * 64 + c4 * 4);
                acc.x += v.x; acc.y += v.y; acc.z += v.z; acc.w += v.w;
            }
        }
    }

    #pragma unroll
    for (int off = 16; off < 64; off <<= 1) {
        acc.x += __shfl_xor(acc.x, off);
        acc.y += __shfl_xor(acc.y, off);
        acc.z += __shfl_xor(acc.z, off);
        acc.w += __shfl_xor(acc.w, off);
    }

    if (sub == 0) {
        float di = dinv[node];
        float4 self = *(const float4*)(t + (size_t)node * 64 + c4 * 4);
        float4 bb   = *(const float4*)(b + c4 * 4);
        float4 r;
        // u1 = di * relu(di*(acc+self) + b)
        r.x = di * fmaxf(di * (acc.x + self.x) + bb.x, 0.f);
        r.y = di * fmaxf(di * (acc.y + self.y) + bb.y, 0.f);
        r.z = di * fmaxf(di * (acc.z + self.z) + bb.z, 0.f);
        r.w = di * fmaxf(di * (acc.w + self.w) + bb.w, 0.f);
        *(float4*)(out + (size_t)node * 64 + c4 * 4) = r;
    }
}

// ---------------- fused hidden layer (persistent waves, W amortized) ----------------
// u = dinv(.)h stored. Per wave: load W column `lane` once into wreg[64]
// (amortized over ~20 grid-stride nodes); per node: gather u, xor-reduce,
// g broadcast via compile-time readlane shuffles (no LDS, no barrier),
// y = g.W + b, store relu (scaled by dinv unless LAST).
template<bool LAST>
__global__ __launch_bounds__(256, 5) void gcn_fused(const int* __restrict__ row_off,
                                                    const int* __restrict__ csr_src,
                                                    const float* __restrict__ dinv,
                                                    const float* __restrict__ u,
                                                    const float* __restrict__ W,
                                                    const float* __restrict__ b,
                                                    float* __restrict__ out, int n) {
    const int tid  = threadIdx.x;
    const int lane = tid & 63;
    const int sub  = lane >> 4;
    const int c4   = lane & 15;

    // W column for my output channel, once per wave lifetime
    float wreg[64];
    #pragma unroll
    for (int cin = 0; cin < 64; ++cin) wreg[cin] = W[cin * 64 + lane];
    const float bl = b[lane];

    const int nwaves = (gridDim.x * blockDim.x) >> 6;
    const int wid0   = (blockIdx.x * blockDim.x + tid) >> 6;

    for (int node = wid0; node < n; node += nwaves) {
        const int base = row_off[node];
        const int end  = row_off[node + 1];

        float4 acc = make_float4(0.f, 0.f, 0.f, 0.f);

        for (int k0 = base; k0 < end; k0 += 64) {
            int myidx = (k0 + lane < end) ? csr_src[k0 + lane] : 0;
            int nk = min(64, end - k0);
            int k = 0;
            for (; k + 8 <= nk; k += 8) {
                int s0 = __shfl(myidx, k + sub);
                int s1 = __shfl(myidx, k + 4 + sub);
                float4 v0 = *(const float4*)(u + (size_t)s0 * 64 + c4 * 4);
                float4 v1 = *(const float4*)(u + (size_t)s1 * 64 + c4 * 4);
                acc.x += v0.x; acc.y += v0.y; acc.z += v0.z; acc.w += v0.w;
                acc.x += v1.x; acc.y += v1.y; acc.z += v1.z; acc.w += v1.w;
            }
            for (; k < nk; k += 4) {
                int kk = k + sub;
                int s = __shfl(myidx, kk);
                if (kk < nk) {
                    float4 v = *(const float4*)(u + (size_t)s * 64 + c4 * 4);
                    acc.x += v.x; acc.y += v.y; acc.z += v.z; acc.w += v.w;
                }
            }
        }

        #pragma unroll
        for (int off = 16; off < 64; off <<= 1) {
            acc.x += __shfl_xor(acc.x, off);
            acc.y += __shfl_xor(acc.y, off);
            acc.z += __shfl_xor(acc.z, off);
            acc.w += __shfl_xor(acc.w, off);
        }

        const float di = dinv[node];
        // every lane computes the g-fragment for its c4 slot (identical across subs)
        float4 self = *(const float4*)(u + (size_t)node * 64 + c4 * 4);
        float4 g;
        g.x = di * (acc.x + self.x);
        g.y = di * (acc.y + self.y);
        g.z = di * (acc.z + self.z);
        g.w = di * (acc.w + self.w);

        // y = g @ W + b via compile-time readlane broadcasts (lane cin>>2 holds g[cin])
        float y = bl;
        #pragma unroll
        for (int q = 0; q < 16; ++q) {
            float g0 = __shfl(g.x, q);
            float g1 = __shfl(g.y, q);
            float g2 = __shfl(g.z, q);
            float g3 = __shfl(g.w, q);
            y = fmaf(g0, wreg[q * 4 + 0], y);
            y = fmaf(g1, wreg[q * 4 + 1], y);
            y = fmaf(g2, wreg[q * 4 + 2], y);
            y = fmaf(g3, wreg[q * 4 + 3], y);
        }
        float h = fmaxf(y, 0.f);
        out[(size_t)node * 64 + lane] = LAST ? h : h * di;
    }
}

// ---------------- pooling via sorted-batch segments ----------------
__global__ void gbounds_kernel(const int* __restrict__ batch, int* __restrict__ gstart, int n) {
    int i = blockIdx.x * blockDim.x + threadIdx.x;
    if (i >= n) return;
    int bi = batch[i];
    int bp = (i == 0) ? -1 : batch[i - 1];
    for (int g = bp + 1; g <= bi; ++g) gstart[g] = i;
    if (i == n - 1) {
        for (int g = bi + 1; g <= Gg; ++g) gstart[g] = n;
    }
}

__global__ __launch_bounds__(256) void pool_graph(const float* __restrict__ h,
                                                  const int* __restrict__ gstart,
                                                  float* __restrict__ pooled) {
    __shared__ float sd[4][64];
    const int g    = blockIdx.x;
    const int lane = threadIdx.x & 63;
    const int wv   = threadIdx.x >> 6;
    const int s = gstart[g], e = gstart[g + 1];
    float acc = 0.f;
    for (int i = s + wv; i < e; i += 4) acc += h[(size_t)i * 64 + lane];
    sd[wv][lane] = acc;
    __syncthreads();
    if (wv == 0) {
        float sum = sd[0][lane] + sd[1][lane] + sd[2][lane] + sd[3][lane];
        float c = (float)(e - s);
        pooled[(size_t)g * 64 + lane] = sum / fmaxf(c, 1.f);
    }
}

// ---------------- MLP head ----------------
__global__ void mlp1_kernel(const float* __restrict__ P, const float* __restrict__ W1,
                            const float* __restrict__ b1, float* __restrict__ H) {
    int gid = blockIdx.x * blockDim.x + threadIdx.x;
    if (gid >= Gg * NHh) return;
    int j = gid & (NHh - 1), g = gid >> 8;
    const float* p = P + (size_t)g * Cc;
    float s = b1[j];
    #pragma unroll 8
    for (int k = 0; k < Cc; ++k) s += p[k] * W1[(size_t)k * NHh + j];
    H[gid] = fmaxf(s, 0.f);
}

__global__ void mlp2_kernel(const float* __restrict__ H, const float* __restrict__ W2,
                            const float* __restrict__ b2, float* __restrict__ O) {
    int gid = blockIdx.x * blockDim.x + threadIdx.x;
    if (gid >= Gg * NOUTt) return;
    int j = gid & (NOUTt - 1), g = gid >> 7;
    const float* h = H + (size_t)g * NHh;
    float s = b2[j];
    #pragma unroll 8
    for (int k = 0; k < NHh; ++k) s += h[k] * W2[(size_t)k * NOUTt + j];
    O[gid] = s;
}

// ---------------- launch ----------------
extern "C" void kernel_launch(void* const* d_in, const int* in_sizes, int n_in,
                              void* d_out, int out_size, void* d_ws, size_t ws_size,
                              hipStream_t stream) {
    const float* x     = (const float*)d_in[0];
    const int*   ei    = (const int*)  d_in[1];
    const int*   batch = (const int*)  d_in[2];
    const float* W0    = (const float*)d_in[3];
    const float* b0    = (const float*)d_in[4];
    const float* Wh    = (const float*)d_in[5];
    const float* bh    = (const float*)d_in[6];
    const float* W1    = (const float*)d_in[7];
    const float* b1    = (const float*)d_in[8];
    const float* W2    = (const float*)d_in[9];
    const float* b2    = (const float*)d_in[10];

    const int* src = ei;
    const int* dst = ei + Ee;

    char* ws = (char*)d_ws;
    constexpr size_t OFF_DINV  = 0;
    constexpr size_t OFF_CNT   = 400384;
    constexpr size_t OFF_ROFF  = OFF_CNT + 400384;
    constexpr size_t OFF_BSUM  = OFF_ROFF + 400384;
    constexpr size_t OFF_BOFF  = OFF_BSUM + 1024;
    constexpr size_t OFF_SCNT  = OFF_BOFF + 1024;
    constexpr size_t OFF_CSR   = OFF_SCNT + 1024;
    constexpr size_t OFF_B     = OFF_CSR + (size_t)Ee * 4;
    constexpr size_t OFF_A     = OFF_B + (size_t)Nn * 64 * 4;
    constexpr size_t OFF_POOL  = OFF_A + (size_t)Nn * 64 * 4;
    constexpr size_t OFF_GST   = OFF_POOL + (size_t)Gg * Cc * 4;
    constexpr size_t OFF_HID   = OFF_GST + 4096;
    const size_t OFF_SB = OFF_B;   // sub-buckets alias B (dead until first gemm)

    float* dinv   = (float*)(ws + OFF_DINV);
    int*   cnt    = (int*)  (ws + OFF_CNT);
    int*   roff   = (int*)  (ws + OFF_ROFF);
    int*   bsum   = (int*)  (ws + OFF_BSUM);
    int*   boff   = (int*)  (ws + OFF_BOFF);
    int*   scnt   = (int*)  (ws + OFF_SCNT);
    int*   csrs   = (int*)  (ws + OFF_CSR);
    int*   sb     = (int*)  (ws + OFF_SB);
    float* B      = (float*)(ws + OFF_B);
    float* A      = (float*)(ws + OFF_A);
    float* pooled = (float*)(ws + OFF_POOL);
    int*   gstart = (int*)  (ws + OFF_GST);
    float* hid    = (float*)(ws + OFF_HID);

    // ---- CSR build: bin -> cnt3 -> scans -> fill3 ----
    hipMemsetAsync(scnt, 0, 1024, stream);
    bin_kernel<<<(Ee + 2047) / 2048, 256, 0, stream>>>(src, dst, sb, scnt, Ee);
    cnt3_kernel<<<NSUB, 512, 0, stream>>>(sb, scnt, cnt);
    dinv_kernel<<<(Nn + 255) / 256, 256, 0, stream>>>(cnt, dinv, Nn);
    scan1_kernel<<<NBLK_SCAN, SCAN_BLK, 0, stream>>>(cnt, roff, bsum, Nn);
    scan2_kernel<<<1, 128, 0, stream>>>(bsum, boff, NBLK_SCAN);
    scan3_kernel<<<(Nn + 255) / 256, 256, 0, stream>>>(roff, boff, Nn);
    fill3_kernel<<<NSUB, 512, 0, stream>>>(sb, scnt, roff, csrs);

    // ---- graph boundaries from sorted batch ----
    gbounds_kernel<<<(Nn + 255) / 256, 256, 0, stream>>>(batch, gstart, Nn);

    const int gemm_blocks  = (Nn + 63) / 64;
    const int agg_blocks   = (Nn * 64 + 255) / 256;
    const int fused_blocks = 1280;    // 5 blocks/CU x 256 CU (persistent waves)

    // ---- layer 0: x @ W0 (scaled) -> gather -> u1 in A ----
    gemm_xw<128><<<gemm_blocks, 256, 0, stream>>>(x, W0, dinv, B, Nn);
    gather_agg<<<agg_blocks, 256, 0, stream>>>(roff, csrs, dinv, B, b0, A, Nn);

    // ---- fused hidden layers (gather + in-register GEMM), ping-pong A/B ----
    gcn_fused<false><<<fused_blocks, 256, 0, stream>>>(roff, csrs, dinv, A,
                                                       Wh + 0 * Cc * Cc, bh + 0 * Cc, B, Nn);
    gcn_fused<false><<<fused_blocks, 256, 0, stream>>>(roff, csrs, dinv, B,
                                                       Wh + 1 * Cc * Cc, bh + 1 * Cc, A, Nn);
    gcn_fused<false><<<fused_blocks, 256, 0, stream>>>(roff, csrs, dinv, A,
                                                       Wh + 2 * Cc * Cc, bh + 2 * Cc, B, Nn);
    gcn_fused<true ><<<fused_blocks, 256, 0, stream>>>(roff, csrs, dinv, B,
                                                       Wh + 3 * Cc * Cc, bh + 3 * Cc, A, Nn);

    // ---- global mean pool (segmented, no atomics) ----
    pool_graph<<<Gg, 256, 0, stream>>>(A, gstart, pooled);

    // ---- MLP head ----
    mlp1_kernel<<<(Gg * NHh + 255) / 256, 256, 0, stream>>>(pooled, W1, b1, hid);
    mlp2_kernel<<<(Gg * NOUTt + 255) / 256, 256, 0, stream>>>(hid, W2, b2, (float*)d_out);
}

// Round 11
// 408.068 us; speedup vs baseline: 2.1324x; 2.1324x over previous
//
#include <hip/hip_runtime.h>
#include <hip/hip_fp16.h>
#include <stddef.h>

static constexpr int Nn    = 100000;   // nodes
static constexpr int Ee    = 1600000;  // edges
static constexpr int Ff    = 128;      // input features
static constexpr int Cc    = 64;       // hidden channels
static constexpr int NHh   = 256;      // nhid
static constexpr int NOUTt = 128;      // nout
static constexpr int Ll    = 4;        // hidden GCN layers
static constexpr int Gg    = 512;      // graphs

static constexpr int SCAN_BLK = 1024;
static constexpr int NBLK_SCAN = (Nn + SCAN_BLK - 1) / SCAN_BLK;   // 98

// R8-proven CSR build: sub-bucket = 512 contiguous nodes; one block owns one
// sub-bucket's csr segment -> dirty lines flush once (write-amp killed).
static constexpr int NSUB   = (Nn + 511) / 512;   // 196
static constexpr int SUBCAP = 10240;

// ---------------- pass 1: bin edges by dst>>9 into 196 sub-buckets ----------------
__global__ __launch_bounds__(256) void bin_kernel(const int* __restrict__ src,
                                                  const int* __restrict__ dst,
                                                  int* __restrict__ sb,
                                                  int* __restrict__ scnt, int E) {
    __shared__ int lcnt[NSUB], lbase[NSUB];
    const int tid = threadIdx.x;
    for (int i = tid; i < NSUB; i += 256) lcnt[i] = 0;
    __syncthreads();
    const int base = blockIdx.x * 2048;
    int pk[8], ps[8], lr[8];
    #pragma unroll
    for (int i = 0; i < 8; ++i) {
        int e = base + i * 256 + tid;
        if (e < E) {
            int d = dst[e], s = src[e];
            int sub = d >> 9;
            ps[i] = sub;
            pk[i] = s | ((d & 511) << 17);
            lr[i] = atomicAdd(&lcnt[sub], 1);
        } else ps[i] = -1;
    }
    __syncthreads();
    for (int i = tid; i < NSUB; i += 256) lbase[i] = atomicAdd(&scnt[i], lcnt[i]);
    __syncthreads();
    #pragma unroll
    for (int i = 0; i < 8; ++i) {
        if (ps[i] >= 0) {
            int pos = lbase[ps[i]] + lr[i];
            if (pos < SUBCAP) sb[(size_t)ps[i] * SUBCAP + pos] = pk[i];
        }
    }
}

// ---------------- pass 2a: per-node degree (one block per sub-bucket) ----------------
__global__ __launch_bounds__(512) void cnt3_kernel(const int* __restrict__ sb,
                                                   const int* __restrict__ scnt,
                                                   int* __restrict__ cnt) {
    __shared__ int lcnt[512];
    const int sub = blockIdx.x, tid = threadIdx.x;
    lcnt[tid] = 0;
    __syncthreads();
    const int n = scnt[sub];
    const int* bp = sb + (size_t)sub * SUBCAP;
    for (int i = tid; i < n; i += 512) atomicAdd(&lcnt[(bp[i] >> 17) & 511], 1);
    __syncthreads();
    int node = sub * 512 + tid;
    if (node < Nn) cnt[node] = lcnt[tid];
}

__global__ void dinv_kernel(const int* __restrict__ cnt, float* __restrict__ dinv, int n) {
    int i = blockIdx.x * blockDim.x + threadIdx.x;
    if (i < n) dinv[i] = rsqrtf((float)cnt[i] + 1.0f);   // + self loop
}

// ---------------- scans ----------------
__global__ __launch_bounds__(SCAN_BLK) void scan1_kernel(const int* __restrict__ cnt,
                                                         int* __restrict__ row_off,
                                                         int* __restrict__ bsum, int n) {
    __shared__ int sd[SCAN_BLK];
    int tid = threadIdx.x;
    int gid = blockIdx.x * SCAN_BLK + tid;
    int v = (gid < n) ? cnt[gid] : 0;
    sd[tid] = v;
    __syncthreads();
    #pragma unroll
    for (int off = 1; off < SCAN_BLK; off <<= 1) {
        int t = (tid >= off) ? sd[tid - off] : 0;
        __syncthreads();
        sd[tid] += t;
        __syncthreads();
    }
    if (gid < n) row_off[gid + 1] = sd[tid];
    if (tid == SCAN_BLK - 1) bsum[blockIdx.x] = sd[tid];
}

__global__ __launch_bounds__(128) void scan2_kernel(const int* __restrict__ bsum,
                                                    int* __restrict__ boff, int nb) {
    __shared__ int sd[128];
    int tid = threadIdx.x;
    sd[tid] = (tid < nb) ? bsum[tid] : 0;
    __syncthreads();
    #pragma unroll
    for (int off = 1; off < 128; off <<= 1) {
        int t = (tid >= off) ? sd[tid - off] : 0;
        __syncthreads();
        sd[tid] += t;
        __syncthreads();
    }
    if (tid < nb) boff[tid] = (tid == 0) ? 0 : sd[tid - 1];
}

__global__ void scan3_kernel(int* __restrict__ row_off, const int* __restrict__ boff, int n) {
    int gid = blockIdx.x * blockDim.x + threadIdx.x;
    if (gid < n) row_off[gid + 1] += boff[gid >> 10];
    if (gid == 0) row_off[0] = 0;
}

// ---------------- pass 2b: fill csr (one block per sub-bucket) ----------------
__global__ __launch_bounds__(512) void fill3_kernel(const int* __restrict__ sb,
                                                    const int* __restrict__ scnt,
                                                    const int* __restrict__ roff,
                                                    int* __restrict__ csr) {
    __shared__ int lcnt[512], lofs[512];
    __shared__ int gbase;
    const int sub = blockIdx.x, tid = threadIdx.x;
    lcnt[tid] = 0;
    if (tid == 0) gbase = roff[sub * 512];
    __syncthreads();
    const int n = scnt[sub];
    const int* bp = sb + (size_t)sub * SUBCAP;
    for (int i = tid; i < n; i += 512) atomicAdd(&lcnt[(bp[i] >> 17) & 511], 1);
    __syncthreads();
    int v = lcnt[tid];
    lofs[tid] = v;
    __syncthreads();
    #pragma unroll
    for (int off = 1; off < 512; off <<= 1) {
        int t = (tid >= off) ? lofs[tid - off] : 0;
        __syncthreads();
        lofs[tid] += t;
        __syncthreads();
    }
    int excl = lofs[tid] - v;
    __syncthreads();
    lcnt[tid] = excl;
    __syncthreads();
    for (int i = tid; i < n; i += 512) {
        int e = bp[i];
        int pos = atomicAdd(&lcnt[(e >> 17) & 511], 1);
        csr[gbase + pos] = e & 0x1FFFF;
    }
}

// ---------------- fp16 helpers ----------------
__device__ inline float4 h4_to_f4(float2 raw) {
    __half2 a = *reinterpret_cast<__half2*>(&raw.x);
    __half2 b = *reinterpret_cast<__half2*>(&raw.y);
    float2 fa = __half22float2(a), fb = __half22float2(b);
    return make_float4(fa.x, fa.y, fb.x, fb.y);
}

// ---------------- GEMM: T[n][64] = fp16( dinv[n] * (X[n][CIN] @ W[CIN][64]) ) ----------------
template<int CIN>
__global__ __launch_bounds__(256) void gemm_xw(const float* __restrict__ X,
                                               const float* __restrict__ W,
                                               const float* __restrict__ dinv,
                                               __half* __restrict__ Y, int n) {
    __shared__ float hs[64][68];
    __shared__ float ws[64][64];
    const int tid = threadIdx.x;
    const int tx  = tid & 15;
    const int ty  = tid >> 4;
    const int rowbase = blockIdx.x * 64;

    float acc[4][4] = {};

    for (int k0 = 0; k0 < CIN; k0 += 64) {
        #pragma unroll
        for (int i = 0; i < 4; ++i) {
            int r = ty + i * 16;
            int gr = rowbase + r;
            float4 v = make_float4(0.f, 0.f, 0.f, 0.f);
            if (gr < n) v = *(const float4*)(X + (size_t)gr * CIN + k0 + tx * 4);
            *(float4*)&hs[r][tx * 4] = v;
        }
        #pragma unroll
        for (int i = 0; i < 4; ++i) {
            int k = ty + i * 16;
            *(float4*)&ws[k][tx * 4] = *(const float4*)(W + (size_t)(k0 + k) * 64 + tx * 4);
        }
        __syncthreads();

        #pragma unroll 4
        for (int k = 0; k < 64; ++k) {
            float4 w = *(const float4*)&ws[k][tx * 4];
            float h0 = hs[ty * 4 + 0][k];
            float h1 = hs[ty * 4 + 1][k];
            float h2 = hs[ty * 4 + 2][k];
            float h3 = hs[ty * 4 + 3][k];
            acc[0][0] += h0 * w.x; acc[0][1] += h0 * w.y; acc[0][2] += h0 * w.z; acc[0][3] += h0 * w.w;
            acc[1][0] += h1 * w.x; acc[1][1] += h1 * w.y; acc[1][2] += h1 * w.z; acc[1][3] += h1 * w.w;
            acc[2][0] += h2 * w.x; acc[2][1] += h2 * w.y; acc[2][2] += h2 * w.z; acc[2][3] += h2 * w.w;
            acc[3][0] += h3 * w.x; acc[3][1] += h3 * w.y; acc[3][2] += h3 * w.z; acc[3][3] += h3 * w.w;
        }
        __syncthreads();
    }

    #pragma unroll
    for (int i = 0; i < 4; ++i) {
        int gr = rowbase + ty * 4 + i;
        if (gr < n) {
            float di = dinv[gr];
            __half2 p0 = __floats2half2_rn(acc[i][0] * di, acc[i][1] * di);
            __half2 p1 = __floats2half2_rn(acc[i][2] * di, acc[i][3] * di);
            float2 st;
            *reinterpret_cast<__half2*>(&st.x) = p0;
            *reinterpret_cast<__half2*>(&st.y) = p1;
            *reinterpret_cast<float2*>(Y + (size_t)gr * 64 + tx * 4) = st;
        }
    }
}

// ---------------- CSR gather-aggregate over fp16 t' (fused finalize, fp32 out) ----------------
// h_out = relu(dinv_i * (sum_nbr t'_j + t'_i) + b); t' fp16 rows = 128B.
__global__ __launch_bounds__(256) void gather_agg(const int* __restrict__ row_off,
                                                  const int* __restrict__ csr_src,
                                                  const float* __restrict__ dinv,
                                                  const __half* __restrict__ t,
                                                  const float* __restrict__ b,
                                                  float* __restrict__ out, int n) {
    const int lane = threadIdx.x & 63;
    const int node = (blockIdx.x * blockDim.x + threadIdx.x) >> 6;
    if (node >= n) return;
    const int sub = lane >> 4;        // 0..3 : edge slot
    const int c4  = lane & 15;        // 4-channel slot within row (8B fp16)

    const int base = row_off[node];
    const int end  = row_off[node + 1];

    float4 acc = make_float4(0.f, 0.f, 0.f, 0.f);

    for (int k0 = base; k0 < end; k0 += 64) {
        int myidx = (k0 + lane < end) ? csr_src[k0 + lane] : 0;
        int nk = min(64, end - k0);
        int k = 0;
        for (; k + 8 <= nk; k += 8) {
            int s0 = __shfl(myidx, k + sub);
            int s1 = __shfl(myidx, k + 4 + sub);
            float2 r0 = *(const float2*)(t + (size_t)s0 * 64 + c4 * 4);
            float2 r1 = *(const float2*)(t + (size_t)s1 * 64 + c4 * 4);
            float4 v0 = h4_to_f4(r0);
            float4 v1 = h4_to_f4(r1);
            acc.x += v0.x; acc.y += v0.y; acc.z += v0.z; acc.w += v0.w;
            acc.x += v1.x; acc.y += v1.y; acc.z += v1.z; acc.w += v1.w;
        }
        for (; k < nk; k += 4) {
            int kk = k + sub;
            int s = __shfl(myidx, kk);
            if (kk < nk) {
                float4 v = h4_to_f4(*(const float2*)(t + (size_t)s * 64 + c4 * 4));
                acc.x += v.x; acc.y += v.y; acc.z += v.z; acc.w += v.w;
            }
        }
    }

    #pragma unroll
    for (int off = 16; off < 64; off <<= 1) {
        acc.x += __shfl_xor(acc.x, off);
        acc.y += __shfl_xor(acc.y, off);
        acc.z += __shfl_xor(acc.z, off);
        acc.w += __shfl_xor(acc.w, off);
    }

    if (sub == 0) {
        float di = dinv[node];
        float4 self = h4_to_f4(*(const float2*)(t + (size_t)node * 64 + c4 * 4));
        float4 bb   = *(const float4*)(b + c4 * 4);
        float4 r;
        r.x = fmaxf(di * (acc.x + self.x) + bb.x, 0.f);
        r.y = fmaxf(di * (acc.y + self.y) + bb.y, 0.f);
        r.z = fmaxf(di * (acc.z + self.z) + bb.z, 0.f);
        r.w = fmaxf(di * (acc.w + self.w) + bb.w, 0.f);
        *(float4*)(out + (size_t)node * 64 + c4 * 4) = r;
    }
}

// ---------------- pooling via sorted-batch segments ----------------
__global__ void gbounds_kernel(const int* __restrict__ batch, int* __restrict__ gstart, int n) {
    int i = blockIdx.x * blockDim.x + threadIdx.x;
    if (i >= n) return;
    int bi = batch[i];
    int bp = (i == 0) ? -1 : batch[i - 1];
    for (int g = bp + 1; g <= bi; ++g) gstart[g] = i;
    if (i == n - 1) {
        for (int g = bi + 1; g <= Gg; ++g) gstart[g] = n;
    }
}

__global__ __launch_bounds__(256) void pool_graph(const float* __restrict__ h,
                                                  const int* __restrict__ gstart,
                                                  float* __restrict__ pooled) {
    __shared__ float sd[4][64];
    const int g    = blockIdx.x;
    const int lane = threadIdx.x & 63;
    const int wv   = threadIdx.x >> 6;
    const int s = gstart[g], e = gstart[g + 1];
    float acc = 0.f;
    for (int i = s + wv; i < e; i += 4) acc += h[(size_t)i * 64 + lane];
    sd[wv][lane] = acc;
    __syncthreads();
    if (wv == 0) {
        float sum = sd[0][lane] + sd[1][lane] + sd[2][lane] + sd[3][lane];
        float c = (float)(e - s);
        pooled[(size_t)g * 64 + lane] = sum / fmaxf(c, 1.f);
    }
}

// ---------------- MLP head ----------------
__global__ void mlp1_kernel(const float* __restrict__ P, const float* __restrict__ W1,
                            const float* __restrict__ b1, float* __restrict__ H) {
    int gid = blockIdx.x * blockDim.x + threadIdx.x;
    if (gid >= Gg * NHh) return;
    int j = gid & (NHh - 1), g = gid >> 8;
    const float* p = P + (size_t)g * Cc;
    float s = b1[j];
    #pragma unroll 8
    for (int k = 0; k < Cc; ++k) s += p[k] * W1[(size_t)k * NHh + j];
    H[gid] = fmaxf(s, 0.f);
}

__global__ void mlp2_kernel(const float* __restrict__ H, const float* __restrict__ W2,
                            const float* __restrict__ b2, float* __restrict__ O) {
    int gid = blockIdx.x * blockDim.x + threadIdx.x;
    if (gid >= Gg * NOUTt) return;
    int j = gid & (NOUTt - 1), g = gid >> 7;
    const float* h = H + (size_t)g * NHh;
    float s = b2[j];
    #pragma unroll 8
    for (int k = 0; k < NHh; ++k) s += h[k] * W2[(size_t)k * NOUTt + j];
    O[gid] = s;
}

// ---------------- launch ----------------
extern "C" void kernel_launch(void* const* d_in, const int* in_sizes, int n_in,
                              void* d_out, int out_size, void* d_ws, size_t ws_size,
                              hipStream_t stream) {
    const float* x     = (const float*)d_in[0];
    const int*   ei    = (const int*)  d_in[1];
    const int*   batch = (const int*)  d_in[2];
    const float* W0    = (const float*)d_in[3];
    const float* b0    = (const float*)d_in[4];
    const float* Wh    = (const float*)d_in[5];
    const float* bh    = (const float*)d_in[6];
    const float* W1    = (const float*)d_in[7];
    const float* b1    = (const float*)d_in[8];
    const float* W2    = (const float*)d_in[9];
    const float* b2    = (const float*)d_in[10];

    const int* src = ei;
    const int* dst = ei + Ee;

    char* ws = (char*)d_ws;
    constexpr size_t OFF_DINV  = 0;
    constexpr size_t OFF_CNT   = 400384;
    constexpr size_t OFF_ROFF  = OFF_CNT + 400384;
    constexpr size_t OFF_BSUM  = OFF_ROFF + 400384;
    constexpr size_t OFF_BOFF  = OFF_BSUM + 1024;
    constexpr size_t OFF_SCNT  = OFF_BOFF + 1024;
    constexpr size_t OFF_CSR   = OFF_SCNT + 1024;
    constexpr size_t OFF_T     = OFF_CSR + 6400256;               // fp16 t' 12.8MB
    constexpr size_t OFF_A     = OFF_T + 12800256;                // fp32 h 25.6MB
    constexpr size_t OFF_POOL  = OFF_A + (size_t)Nn * 64 * 4;
    constexpr size_t OFF_GST   = OFF_POOL + (size_t)Gg * Cc * 4;
    constexpr size_t OFF_HID   = OFF_GST + 4096;
    const size_t OFF_SB = OFF_T;   // sub-buckets (8.03MB) alias T (dead until gemm)

    float*  dinv   = (float*) (ws + OFF_DINV);
    int*    cnt    = (int*)   (ws + OFF_CNT);
    int*    roff   = (int*)   (ws + OFF_ROFF);
    int*    bsum   = (int*)   (ws + OFF_BSUM);
    int*    boff   = (int*)   (ws + OFF_BOFF);
    int*    scnt   = (int*)   (ws + OFF_SCNT);
    int*    csrs   = (int*)   (ws + OFF_CSR);
    int*    sb     = (int*)   (ws + OFF_SB);
    __half* T      = (__half*)(ws + OFF_T);
    float*  A      = (float*) (ws + OFF_A);
    float*  pooled = (float*) (ws + OFF_POOL);
    int*    gstart = (int*)   (ws + OFF_GST);
    float*  hid    = (float*) (ws + OFF_HID);

    // ---- CSR build: bin -> cnt3 -> scans -> fill3 ----
    hipMemsetAsync(scnt, 0, 1024, stream);
    bin_kernel<<<(Ee + 2047) / 2048, 256, 0, stream>>>(src, dst, sb, scnt, Ee);
    cnt3_kernel<<<NSUB, 512, 0, stream>>>(sb, scnt, cnt);
    dinv_kernel<<<(Nn + 255) / 256, 256, 0, stream>>>(cnt, dinv, Nn);
    scan1_kernel<<<NBLK_SCAN, SCAN_BLK, 0, stream>>>(cnt, roff, bsum, Nn);
    scan2_kernel<<<1, 128, 0, stream>>>(bsum, boff, NBLK_SCAN);
    scan3_kernel<<<(Nn + 255) / 256, 256, 0, stream>>>(roff, boff, Nn);
    fill3_kernel<<<NSUB, 512, 0, stream>>>(sb, scnt, roff, csrs);

    // ---- graph boundaries from sorted batch ----
    gbounds_kernel<<<(Nn + 255) / 256, 256, 0, stream>>>(batch, gstart, Nn);

    const int gemm_blocks = (Nn + 63) / 64;
    const int agg_blocks  = (Nn * 64 + 255) / 256;

    // ---- layer 0: x @ W0 (dinv-scaled, fp16) -> gather -> h in A ----
    gemm_xw<128><<<gemm_blocks, 256, 0, stream>>>(x, W0, dinv, T, Nn);
    gather_agg<<<agg_blocks, 256, 0, stream>>>(roff, csrs, dinv, T, b0, A, Nn);

    // ---- hidden layers: gemm(A -> T fp16), gather(T -> A in place) ----
    for (int i = 0; i < Ll; ++i) {
        gemm_xw<64><<<gemm_blocks, 256, 0, stream>>>(A, Wh + (size_t)i * Cc * Cc, dinv, T, Nn);
        gather_agg<<<agg_blocks, 256, 0, stream>>>(roff, csrs, dinv, T, bh + (size_t)i * Cc, A, Nn);
    }

    // ---- global mean pool (segmented, no atomics) ----
    pool_graph<<<Gg, 256, 0, stream>>>(A, gstart, pooled);

    // ---- MLP head ----
    mlp1_kernel<<<(Gg * NHh + 255) / 256, 256, 0, stream>>>(pooled, W1, b1, hid);
    mlp2_kernel<<<(Gg * NOUTt + 255) / 256, 256, 0, stream>>>(hid, W2, b2, (float*)d_out);
}

// Round 12
// 406.803 us; speedup vs baseline: 2.1390x; 1.0031x over previous
//
#include <hip/hip_runtime.h>
#include <hip/hip_fp16.h>
#include <stddef.h>

static constexpr int Nn    = 100000;   // nodes
static constexpr int Ee    = 1600000;  // edges
static constexpr int Ff    = 128;      // input features
static constexpr int Cc    = 64;       // hidden channels
static constexpr int NHh   = 256;      // nhid
static constexpr int NOUTt = 128;      // nout
static constexpr int Ll    = 4;        // hidden GCN layers
static constexpr int Gg    = 512;      // graphs

static constexpr int SCAN_BLK = 1024;
static constexpr int NBLK_SCAN = (Nn + SCAN_BLK - 1) / SCAN_BLK;   // 98

// R8-proven CSR build: sub-bucket = 512 contiguous nodes; one block owns one
// sub-bucket's csr segment -> dirty lines flush once (write-amp killed).
static constexpr int NSUB   = (Nn + 511) / 512;   // 196
static constexpr int SUBCAP = 10240;

// ---------------- pass 1: bin edges by dst>>9 into 196 sub-buckets ----------------
__global__ __launch_bounds__(256) void bin_kernel(const int* __restrict__ src,
                                                  const int* __restrict__ dst,
                                                  int* __restrict__ sb,
                                                  int* __restrict__ scnt, int E) {
    __shared__ int lcnt[NSUB], lbase[NSUB];
    const int tid = threadIdx.x;
    for (int i = tid; i < NSUB; i += 256) lcnt[i] = 0;
    __syncthreads();
    const int base = blockIdx.x * 2048;
    int pk[8], ps[8], lr[8];
    #pragma unroll
    for (int i = 0; i < 8; ++i) {
        int e = base + i * 256 + tid;
        if (e < E) {
            int d = dst[e], s = src[e];
            int sub = d >> 9;
            ps[i] = sub;
            pk[i] = s | ((d & 511) << 17);
            lr[i] = atomicAdd(&lcnt[sub], 1);
        } else ps[i] = -1;
    }
    __syncthreads();
    for (int i = tid; i < NSUB; i += 256) lbase[i] = atomicAdd(&scnt[i], lcnt[i]);
    __syncthreads();
    #pragma unroll
    for (int i = 0; i < 8; ++i) {
        if (ps[i] >= 0) {
            int pos = lbase[ps[i]] + lr[i];
            if (pos < SUBCAP) sb[(size_t)ps[i] * SUBCAP + pos] = pk[i];
        }
    }
}

// ---------------- pass 2a: per-node degree (one block per sub-bucket) ----------------
__global__ __launch_bounds__(512) void cnt3_kernel(const int* __restrict__ sb,
                                                   const int* __restrict__ scnt,
                                                   int* __restrict__ cnt) {
    __shared__ int lcnt[512];
    const int sub = blockIdx.x, tid = threadIdx.x;
    lcnt[tid] = 0;
    __syncthreads();
    const int n = scnt[sub];
    const int* bp = sb + (size_t)sub * SUBCAP;
    for (int i = tid; i < n; i += 512) atomicAdd(&lcnt[(bp[i] >> 17) & 511], 1);
    __syncthreads();
    int node = sub * 512 + tid;
    if (node < Nn) cnt[node] = lcnt[tid];
}

__global__ void dinv_kernel(const int* __restrict__ cnt, float* __restrict__ dinv, int n) {
    int i = blockIdx.x * blockDim.x + threadIdx.x;
    if (i < n) dinv[i] = rsqrtf((float)cnt[i] + 1.0f);   // + self loop
}

// ---------------- scans ----------------
__global__ __launch_bounds__(SCAN_BLK) void scan1_kernel(const int* __restrict__ cnt,
                                                         int* __restrict__ row_off,
                                                         int* __restrict__ bsum, int n) {
    __shared__ int sd[SCAN_BLK];
    int tid = threadIdx.x;
    int gid = blockIdx.x * SCAN_BLK + tid;
    int v = (gid < n) ? cnt[gid] : 0;
    sd[tid] = v;
    __syncthreads();
    #pragma unroll
    for (int off = 1; off < SCAN_BLK; off <<= 1) {
        int t = (tid >= off) ? sd[tid - off] : 0;
        __syncthreads();
        sd[tid] += t;
        __syncthreads();
    }
    if (gid < n) row_off[gid + 1] = sd[tid];
    if (tid == SCAN_BLK - 1) bsum[blockIdx.x] = sd[tid];
}

__global__ __launch_bounds__(128) void scan2_kernel(const int* __restrict__ bsum,
                                                    int* __restrict__ boff, int nb) {
    __shared__ int sd[128];
    int tid = threadIdx.x;
    sd[tid] = (tid < nb) ? bsum[tid] : 0;
    __syncthreads();
    #pragma unroll
    for (int off = 1; off < 128; off <<= 1) {
        int t = (tid >= off) ? sd[tid - off] : 0;
        __syncthreads();
        sd[tid] += t;
        __syncthreads();
    }
    if (tid < nb) boff[tid] = (tid == 0) ? 0 : sd[tid - 1];
}

__global__ void scan3_kernel(int* __restrict__ row_off, const int* __restrict__ boff, int n) {
    int gid = blockIdx.x * blockDim.x + threadIdx.x;
    if (gid < n) row_off[gid + 1] += boff[gid >> 10];
    if (gid == 0) row_off[0] = 0;
}

// ---------------- pass 2b: fill csr (one block per sub-bucket) ----------------
__global__ __launch_bounds__(512) void fill3_kernel(const int* __restrict__ sb,
                                                    const int* __restrict__ scnt,
                                                    const int* __restrict__ roff,
                                                    int* __restrict__ csr) {
    __shared__ int lcnt[512], lofs[512];
    __shared__ int gbase;
    const int sub = blockIdx.x, tid = threadIdx.x;
    lcnt[tid] = 0;
    if (tid == 0) gbase = roff[sub * 512];
    __syncthreads();
    const int n = scnt[sub];
    const int* bp = sb + (size_t)sub * SUBCAP;
    for (int i = tid; i < n; i += 512) atomicAdd(&lcnt[(bp[i] >> 17) & 511], 1);
    __syncthreads();
    int v = lcnt[tid];
    lofs[tid] = v;
    __syncthreads();
    #pragma unroll
    for (int off = 1; off < 512; off <<= 1) {
        int t = (tid >= off) ? lofs[tid - off] : 0;
        __syncthreads();
        lofs[tid] += t;
        __syncthreads();
    }
    int excl = lofs[tid] - v;
    __syncthreads();
    lcnt[tid] = excl;
    __syncthreads();
    for (int i = tid; i < n; i += 512) {
        int e = bp[i];
        int pos = atomicAdd(&lcnt[(e >> 17) & 511], 1);
        csr[gbase + pos] = e & 0x1FFFF;
    }
}

// ---------------- fp16 helpers ----------------
__device__ inline void add_h8(float acc[8], float4 raw) {
    const __half2* hp = reinterpret_cast<const __half2*>(&raw);
    #pragma unroll
    for (int j = 0; j < 4; ++j) {
        float2 f = __half22float2(hp[j]);
        acc[2 * j]     += f.x;
        acc[2 * j + 1] += f.y;
    }
}

__device__ inline void cvt_h8(float4 raw, float v[8]) {
    const __half2* hp = reinterpret_cast<const __half2*>(&raw);
    #pragma unroll
    for (int j = 0; j < 4; ++j) {
        float2 f = __half22float2(hp[j]);
        v[2 * j] = f.x; v[2 * j + 1] = f.y;
    }
}

// ---------------- GEMM layer0: T = fp16( dinv * (X_f32 @ W) ) ----------------
__global__ __launch_bounds__(256) void gemm_xw_f32(const float* __restrict__ X,
                                                   const float* __restrict__ W,
                                                   const float* __restrict__ dinv,
                                                   __half* __restrict__ Y, int n) {
    __shared__ float hs[64][68];
    __shared__ float ws[64][64];
    const int tid = threadIdx.x;
    const int tx  = tid & 15;
    const int ty  = tid >> 4;
    const int rowbase = blockIdx.x * 64;

    float acc[4][4] = {};

    for (int k0 = 0; k0 < Ff; k0 += 64) {
        #pragma unroll
        for (int i = 0; i < 4; ++i) {
            int r = ty + i * 16;
            int gr = rowbase + r;
            float4 v = make_float4(0.f, 0.f, 0.f, 0.f);
            if (gr < n) v = *(const float4*)(X + (size_t)gr * Ff + k0 + tx * 4);
            *(float4*)&hs[r][tx * 4] = v;
        }
        #pragma unroll
        for (int i = 0; i < 4; ++i) {
            int k = ty + i * 16;
            *(float4*)&ws[k][tx * 4] = *(const float4*)(W + (size_t)(k0 + k) * 64 + tx * 4);
        }
        __syncthreads();

        #pragma unroll 4
        for (int k = 0; k < 64; ++k) {
            float4 w = *(const float4*)&ws[k][tx * 4];
            float h0 = hs[ty * 4 + 0][k];
            float h1 = hs[ty * 4 + 1][k];
            float h2 = hs[ty * 4 + 2][k];
            float h3 = hs[ty * 4 + 3][k];
            acc[0][0] += h0 * w.x; acc[0][1] += h0 * w.y; acc[0][2] += h0 * w.z; acc[0][3] += h0 * w.w;
            acc[1][0] += h1 * w.x; acc[1][1] += h1 * w.y; acc[1][2] += h1 * w.z; acc[1][3] += h1 * w.w;
            acc[2][0] += h2 * w.x; acc[2][1] += h2 * w.y; acc[2][2] += h2 * w.z; acc[2][3] += h2 * w.w;
            acc[3][0] += h3 * w.x; acc[3][1] += h3 * w.y; acc[3][2] += h3 * w.z; acc[3][3] += h3 * w.w;
        }
        __syncthreads();
    }

    #pragma unroll
    for (int i = 0; i < 4; ++i) {
        int gr = rowbase + ty * 4 + i;
        if (gr < n) {
            float di = dinv[gr];
            __half2 p0 = __floats2half2_rn(acc[i][0] * di, acc[i][1] * di);
            __half2 p1 = __floats2half2_rn(acc[i][2] * di, acc[i][3] * di);
            float2 st;
            *reinterpret_cast<__half2*>(&st.x) = p0;
            *reinterpret_cast<__half2*>(&st.y) = p1;
            *reinterpret_cast<float2*>(Y + (size_t)gr * 64 + tx * 4) = st;
        }
    }
}

// ---------------- GEMM hidden: T = fp16( dinv * (H_f16 @ W) ) ----------------
__global__ __launch_bounds__(256) void gemm_xw_f16(const __half* __restrict__ X,
                                                   const float* __restrict__ W,
                                                   const float* __restrict__ dinv,
                                                   __half* __restrict__ Y, int n) {
    __shared__ float hs[64][68];
    __shared__ float ws[64][64];
    const int tid = threadIdx.x;
    const int tx  = tid & 15;
    const int ty  = tid >> 4;
    const int rowbase = blockIdx.x * 64;

    float acc[4][4] = {};

    // stage fp16 -> fp32 LDS
    #pragma unroll
    for (int i = 0; i < 4; ++i) {
        int r = ty + i * 16;
        int gr = rowbase + r;
        float4 v = make_float4(0.f, 0.f, 0.f, 0.f);
        if (gr < n) {
            float2 raw = *(const float2*)(X + (size_t)gr * 64 + tx * 4);  // 4 halfs
            __half2 a = *reinterpret_cast<__half2*>(&raw.x);
            __half2 b = *reinterpret_cast<__half2*>(&raw.y);
            float2 fa = __half22float2(a), fb = __half22float2(b);
            v = make_float4(fa.x, fa.y, fb.x, fb.y);
        }
        *(float4*)&hs[r][tx * 4] = v;
    }
    #pragma unroll
    for (int i = 0; i < 4; ++i) {
        int k = ty + i * 16;
        *(float4*)&ws[k][tx * 4] = *(const float4*)(W + (size_t)k * 64 + tx * 4);
    }
    __syncthreads();

    #pragma unroll 4
    for (int k = 0; k < 64; ++k) {
        float4 w = *(const float4*)&ws[k][tx * 4];
        float h0 = hs[ty * 4 + 0][k];
        float h1 = hs[ty * 4 + 1][k];
        float h2 = hs[ty * 4 + 2][k];
        float h3 = hs[ty * 4 + 3][k];
        acc[0][0] += h0 * w.x; acc[0][1] += h0 * w.y; acc[0][2] += h0 * w.z; acc[0][3] += h0 * w.w;
        acc[1][0] += h1 * w.x; acc[1][1] += h1 * w.y; acc[1][2] += h1 * w.z; acc[1][3] += h1 * w.w;
        acc[2][0] += h2 * w.x; acc[2][1] += h2 * w.y; acc[2][2] += h2 * w.z; acc[2][3] += h2 * w.w;
        acc[3][0] += h3 * w.x; acc[3][1] += h3 * w.y; acc[3][2] += h3 * w.z; acc[3][3] += h3 * w.w;
    }

    #pragma unroll
    for (int i = 0; i < 4; ++i) {
        int gr = rowbase + ty * 4 + i;
        if (gr < n) {
            float di = dinv[gr];
            __half2 p0 = __floats2half2_rn(acc[i][0] * di, acc[i][1] * di);
            __half2 p1 = __floats2half2_rn(acc[i][2] * di, acc[i][3] * di);
            float2 st;
            *reinterpret_cast<__half2*>(&st.x) = p0;
            *reinterpret_cast<__half2*>(&st.y) = p1;
            *reinterpret_cast<float2*>(Y + (size_t)gr * 64 + tx * 4) = st;
        }
    }
}

// ---------------- CSR gather-aggregate over fp16 t' -> fp16 h ----------------
// 8 subgroups of 8 lanes; each subgroup handles one edge row; lane reads 16B
// (8 fp16 channels). h_out = relu(dinv_i*(sum t'_j + t'_i) + b), stored fp16.
__global__ __launch_bounds__(256) void gather_agg(const int* __restrict__ row_off,
                                                  const int* __restrict__ csr_src,
                                                  const float* __restrict__ dinv,
                                                  const __half* __restrict__ t,
                                                  const float* __restrict__ b,
                                                  __half* __restrict__ out, int n) {
    const int lane = threadIdx.x & 63;
    const int node = (blockIdx.x * blockDim.x + threadIdx.x) >> 6;
    if (node >= n) return;
    const int sub = lane >> 3;        // 0..7 : edge slot
    const int c8  = lane & 7;         // 8-channel block (16B)

    const int base = row_off[node];
    const int end  = row_off[node + 1];

    float acc[8] = {};

    for (int k0 = base; k0 < end; k0 += 64) {
        int myidx = (k0 + lane < end) ? csr_src[k0 + lane] : 0;
        int nk = min(64, end - k0);
        int k = 0;
        for (; k + 16 <= nk; k += 16) {
            int s0 = __shfl(myidx, k + sub);
            int s1 = __shfl(myidx, k + 8 + sub);
            float4 r0 = *(const float4*)(t + (size_t)s0 * 64 + c8 * 8);
            float4 r1 = *(const float4*)(t + (size_t)s1 * 64 + c8 * 8);
            add_h8(acc, r0);
            add_h8(acc, r1);
        }
        for (; k < nk; k += 8) {
            int kk = k + sub;
            int s = __shfl(myidx, kk);
            if (kk < nk) {
                float4 r = *(const float4*)(t + (size_t)s * 64 + c8 * 8);
                add_h8(acc, r);
            }
        }
    }

    // reduce across the 8 sub-groups (lanes differing in bits 3,4,5)
    #pragma unroll
    for (int off = 8; off < 64; off <<= 1) {
        #pragma unroll
        for (int j = 0; j < 8; ++j) acc[j] += __shfl_xor(acc[j], off);
    }

    if (sub == 0) {
        float di = dinv[node];
        float selfv[8];
        cvt_h8(*(const float4*)(t + (size_t)node * 64 + c8 * 8), selfv);
        float4 b0 = *(const float4*)(b + c8 * 8);
        float4 b1 = *(const float4*)(b + c8 * 8 + 4);
        float bb[8] = {b0.x, b0.y, b0.z, b0.w, b1.x, b1.y, b1.z, b1.w};
        __half2 o[4];
        #pragma unroll
        for (int j = 0; j < 4; ++j) {
            float v0 = fmaxf(di * (acc[2 * j]     + selfv[2 * j])     + bb[2 * j],     0.f);
            float v1 = fmaxf(di * (acc[2 * j + 1] + selfv[2 * j + 1]) + bb[2 * j + 1], 0.f);
            o[j] = __floats2half2_rn(v0, v1);
        }
        *(float4*)(out + (size_t)node * 64 + c8 * 8) = *reinterpret_cast<float4*>(o);
    }
}

// ---------------- pooling via sorted-batch segments ----------------
__global__ void gbounds_kernel(const int* __restrict__ batch, int* __restrict__ gstart, int n) {
    int i = blockIdx.x * blockDim.x + threadIdx.x;
    if (i >= n) return;
    int bi = batch[i];
    int bp = (i == 0) ? -1 : batch[i - 1];
    for (int g = bp + 1; g <= bi; ++g) gstart[g] = i;
    if (i == n - 1) {
        for (int g = bi + 1; g <= Gg; ++g) gstart[g] = n;
    }
}

__global__ __launch_bounds__(256) void pool_graph(const __half* __restrict__ h,
                                                  const int* __restrict__ gstart,
                                                  float* __restrict__ pooled) {
    __shared__ float sd[4][64];
    const int g    = blockIdx.x;
    const int lane = threadIdx.x & 63;
    const int wv   = threadIdx.x >> 6;
    const int s = gstart[g], e = gstart[g + 1];
    float acc = 0.f;
    for (int i = s + wv; i < e; i += 4) acc += __half2float(h[(size_t)i * 64 + lane]);
    sd[wv][lane] = acc;
    __syncthreads();
    if (wv == 0) {
        float sum = sd[0][lane] + sd[1][lane] + sd[2][lane] + sd[3][lane];
        float c = (float)(e - s);
        pooled[(size_t)g * 64 + lane] = sum / fmaxf(c, 1.f);
    }
}

// ---------------- MLP head ----------------
__global__ void mlp1_kernel(const float* __restrict__ P, const float* __restrict__ W1,
                            const float* __restrict__ b1, float* __restrict__ H) {
    int gid = blockIdx.x * blockDim.x + threadIdx.x;
    if (gid >= Gg * NHh) return;
    int j = gid & (NHh - 1), g = gid >> 8;
    const float* p = P + (size_t)g * Cc;
    float s = b1[j];
    #pragma unroll 8
    for (int k = 0; k < Cc; ++k) s += p[k] * W1[(size_t)k * NHh + j];
    H[gid] = fmaxf(s, 0.f);
}

__global__ void mlp2_kernel(const float* __restrict__ H, const float* __restrict__ W2,
                            const float* __restrict__ b2, float* __restrict__ O) {
    int gid = blockIdx.x * blockDim.x + threadIdx.x;
    if (gid >= Gg * NOUTt) return;
    int j = gid & (NOUTt - 1), g = gid >> 7;
    const float* h = H + (size_t)g * NHh;
    float s = b2[j];
    #pragma unroll 8
    for (int k = 0; k < NHh; ++k) s += h[k] * W2[(size_t)k * NOUTt + j];
    O[gid] = s;
}

// ---------------- launch ----------------
extern "C" void kernel_launch(void* const* d_in, const int* in_sizes, int n_in,
                              void* d_out, int out_size, void* d_ws, size_t ws_size,
                              hipStream_t stream) {
    const float* x     = (const float*)d_in[0];
    const int*   ei    = (const int*)  d_in[1];
    const int*   batch = (const int*)  d_in[2];
    const float* W0    = (const float*)d_in[3];
    const float* b0    = (const float*)d_in[4];
    const float* Wh    = (const float*)d_in[5];
    const float* bh    = (const float*)d_in[6];
    const float* W1    = (const float*)d_in[7];
    const float* b1    = (const float*)d_in[8];
    const float* W2    = (const float*)d_in[9];
    const float* b2    = (const float*)d_in[10];

    const int* src = ei;
    const int* dst = ei + Ee;

    char* ws = (char*)d_ws;
    constexpr size_t OFF_DINV  = 0;
    constexpr size_t OFF_CNT   = 400384;
    constexpr size_t OFF_ROFF  = OFF_CNT + 400384;
    constexpr size_t OFF_BSUM  = OFF_ROFF + 400384;
    constexpr size_t OFF_BOFF  = OFF_BSUM + 1024;
    constexpr size_t OFF_SCNT  = OFF_BOFF + 1024;
    constexpr size_t OFF_CSR   = OFF_SCNT + 1024;
    constexpr size_t OFF_T     = OFF_CSR + 6400256;               // fp16 t' 12.8MB
    constexpr size_t OFF_A     = OFF_T + 12800256;                // fp16 h 12.8MB
    constexpr size_t OFF_POOL  = OFF_A + 12800256;
    constexpr size_t OFF_GST   = OFF_POOL + (size_t)Gg * Cc * 4;
    constexpr size_t OFF_HID   = OFF_GST + 4096;
    const size_t OFF_SB = OFF_T;   // sub-buckets (8.03MB) alias T (dead until gemm)

    float*  dinv   = (float*) (ws + OFF_DINV);
    int*    cnt    = (int*)   (ws + OFF_CNT);
    int*    roff   = (int*)   (ws + OFF_ROFF);
    int*    bsum   = (int*)   (ws + OFF_BSUM);
    int*    boff   = (int*)   (ws + OFF_BOFF);
    int*    scnt   = (int*)   (ws + OFF_SCNT);
    int*    csrs   = (int*)   (ws + OFF_CSR);
    int*    sb     = (int*)   (ws + OFF_SB);
    __half* T      = (__half*)(ws + OFF_T);
    __half* A      = (__half*)(ws + OFF_A);
    float*  pooled = (float*) (ws + OFF_POOL);
    int*    gstart = (int*)   (ws + OFF_GST);
    float*  hid    = (float*) (ws + OFF_HID);

    // ---- CSR build: bin -> cnt3 -> scans -> fill3 ----
    hipMemsetAsync(scnt, 0, 1024, stream);
    bin_kernel<<<(Ee + 2047) / 2048, 256, 0, stream>>>(src, dst, sb, scnt, Ee);
    cnt3_kernel<<<NSUB, 512, 0, stream>>>(sb, scnt, cnt);
    dinv_kernel<<<(Nn + 255) / 256, 256, 0, stream>>>(cnt, dinv, Nn);
    scan1_kernel<<<NBLK_SCAN, SCAN_BLK, 0, stream>>>(cnt, roff, bsum, Nn);
    scan2_kernel<<<1, 128, 0, stream>>>(bsum, boff, NBLK_SCAN);
    scan3_kernel<<<(Nn + 255) / 256, 256, 0, stream>>>(roff, boff, Nn);
    fill3_kernel<<<NSUB, 512, 0, stream>>>(sb, scnt, roff, csrs);

    // ---- graph boundaries from sorted batch ----
    gbounds_kernel<<<(Nn + 255) / 256, 256, 0, stream>>>(batch, gstart, Nn);

    const int gemm_blocks = (Nn + 63) / 64;
    const int agg_blocks  = (Nn * 64 + 255) / 256;

    // ---- layer 0: x @ W0 (dinv-scaled, fp16) -> gather -> h(fp16) in A ----
    gemm_xw_f32<<<gemm_blocks, 256, 0, stream>>>(x, W0, dinv, T, Nn);
    gather_agg<<<agg_blocks, 256, 0, stream>>>(roff, csrs, dinv, T, b0, A, Nn);

    // ---- hidden layers: gemm(A fp16 -> T fp16), gather(T -> A) ----
    for (int i = 0; i < Ll; ++i) {
        gemm_xw_f16<<<gemm_blocks, 256, 0, stream>>>(A, Wh + (size_t)i * Cc * Cc, dinv, T, Nn);
        gather_agg<<<agg_blocks, 256, 0, stream>>>(roff, csrs, dinv, T, bh + (size_t)i * Cc, A, Nn);
    }

    // ---- global mean pool (segmented, no atomics) ----
    pool_graph<<<Gg, 256, 0, stream>>>(A, gstart, pooled);

    // ---- MLP head ----
    mlp1_kernel<<<(Gg * NHh + 255) / 256, 256, 0, stream>>>(pooled, W1, b1, hid);
    mlp2_kernel<<<(Gg * NOUTt + 255) / 256, 256, 0, stream>>>(hid, W2, b2, (float*)d_out);
}

// Round 13
// 372.442 us; speedup vs baseline: 2.3364x; 1.0923x over previous
//
#include <hip/hip_runtime.h>
#include <hip/hip_fp16.h>
#include <stddef.h>

static constexpr int Nn    = 100000;
static constexpr int Ee    = 1600000;
static constexpr int Ff    = 128;
static constexpr int Cc    = 64;
static constexpr int NHh   = 256;
static constexpr int NOUTt = 128;
static constexpr int Ll    = 4;
static constexpr int Gg    = 512;

static constexpr int SCAN_BLK = 1024;
static constexpr int NBLK_SCAN = (Nn + SCAN_BLK - 1) / SCAN_BLK;   // 98

static constexpr int NSUB   = (Nn + 511) / 512;   // 196
static constexpr int SUBCAP = 10240;

typedef _Float16 half8 __attribute__((ext_vector_type(8)));
typedef float    f32x4 __attribute__((ext_vector_type(4)));

// ---------------- pass 1: bin edges by dst>>9 into 196 sub-buckets ----------------
__global__ __launch_bounds__(256) void bin_kernel(const int* __restrict__ src,
                                                  const int* __restrict__ dst,
                                                  int* __restrict__ sb,
                                                  int* __restrict__ scnt, int E) {
    __shared__ int lcnt[NSUB], lbase[NSUB];
    const int tid = threadIdx.x;
    for (int i = tid; i < NSUB; i += 256) lcnt[i] = 0;
    __syncthreads();
    const int base = blockIdx.x * 2048;
    int pk[8], ps[8], lr[8];
    #pragma unroll
    for (int i = 0; i < 8; ++i) {
        int e = base + i * 256 + tid;
        if (e < E) {
            int d = dst[e], s = src[e];
            int sub = d >> 9;
            ps[i] = sub;
            pk[i] = s | ((d & 511) << 17);
            lr[i] = atomicAdd(&lcnt[sub], 1);
        } else ps[i] = -1;
    }
    __syncthreads();
    for (int i = tid; i < NSUB; i += 256) lbase[i] = atomicAdd(&scnt[i], lcnt[i]);
    __syncthreads();
    #pragma unroll
    for (int i = 0; i < 8; ++i) {
        if (ps[i] >= 0) {
            int pos = lbase[ps[i]] + lr[i];
            if (pos < SUBCAP) sb[(size_t)ps[i] * SUBCAP + pos] = pk[i];
        }
    }
}

// ---------------- pass 2a: degree + dinv (one block per sub-bucket) ----------------
__global__ __launch_bounds__(512) void cnt3_kernel(const int* __restrict__ sb,
                                                   const int* __restrict__ scnt,
                                                   int* __restrict__ cnt,
                                                   float* __restrict__ dinv) {
    __shared__ int lcnt[512];
    const int sub = blockIdx.x, tid = threadIdx.x;
    lcnt[tid] = 0;
    __syncthreads();
    const int n = scnt[sub];
    const int* bp = sb + (size_t)sub * SUBCAP;
    for (int i = tid; i < n; i += 512) atomicAdd(&lcnt[(bp[i] >> 17) & 511], 1);
    __syncthreads();
    int node = sub * 512 + tid;
    if (node < Nn) {
        cnt[node] = lcnt[tid];
        dinv[node] = rsqrtf((float)lcnt[tid] + 1.0f);
    }
}

// ---------------- scans ----------------
__global__ __launch_bounds__(SCAN_BLK) void scan1_kernel(const int* __restrict__ cnt,
                                                         int* __restrict__ row_off,
                                                         int* __restrict__ bsum, int n) {
    __shared__ int sd[SCAN_BLK];
    int tid = threadIdx.x;
    int gid = blockIdx.x * SCAN_BLK + tid;
    int v = (gid < n) ? cnt[gid] : 0;
    sd[tid] = v;
    __syncthreads();
    #pragma unroll
    for (int off = 1; off < SCAN_BLK; off <<= 1) {
        int t = (tid >= off) ? sd[tid - off] : 0;
        __syncthreads();
        sd[tid] += t;
        __syncthreads();
    }
    if (gid < n) row_off[gid + 1] = sd[tid];
    if (tid == SCAN_BLK - 1) bsum[blockIdx.x] = sd[tid];
}

__global__ __launch_bounds__(128) void scan2_kernel(const int* __restrict__ bsum,
                                                    int* __restrict__ boff, int nb) {
    __shared__ int sd[128];
    int tid = threadIdx.x;
    sd[tid] = (tid < nb) ? bsum[tid] : 0;
    __syncthreads();
    #pragma unroll
    for (int off = 1; off < 128; off <<= 1) {
        int t = (tid >= off) ? sd[tid - off] : 0;
        __syncthreads();
        sd[tid] += t;
        __syncthreads();
    }
    if (tid < nb) boff[tid] = (tid == 0) ? 0 : sd[tid - 1];
}

// finalize row_off + graph boundaries (merged gbounds)
__global__ void scan3_kernel(int* __restrict__ row_off, const int* __restrict__ boff,
                             const int* __restrict__ batch, int* __restrict__ gstart, int n) {
    int gid = blockIdx.x * blockDim.x + threadIdx.x;
    if (gid < n) {
        row_off[gid + 1] += boff[gid >> 10];
        int bi = batch[gid];
        int bp = (gid == 0) ? -1 : batch[gid - 1];
        for (int g = bp + 1; g <= bi; ++g) gstart[g] = gid;
        if (gid == n - 1) {
            for (int g = bi + 1; g <= Gg; ++g) gstart[g] = n;
        }
    }
    if (gid == 0) row_off[0] = 0;
}

// ---------------- pass 2b: fill csr (one block per sub-bucket) ----------------
__global__ __launch_bounds__(512) void fill3_kernel(const int* __restrict__ sb,
                                                    const int* __restrict__ scnt,
                                                    const int* __restrict__ roff,
                                                    int* __restrict__ csr) {
    __shared__ int lcnt[512], lofs[512];
    __shared__ int gbase;
    const int sub = blockIdx.x, tid = threadIdx.x;
    lcnt[tid] = 0;
    if (tid == 0) gbase = roff[sub * 512];
    __syncthreads();
    const int n = scnt[sub];
    const int* bp = sb + (size_t)sub * SUBCAP;
    for (int i = tid; i < n; i += 512) atomicAdd(&lcnt[(bp[i] >> 17) & 511], 1);
    __syncthreads();
    int v = lcnt[tid];
    lofs[tid] = v;
    __syncthreads();
    #pragma unroll
    for (int off = 1; off < 512; off <<= 1) {
        int t = (tid >= off) ? lofs[tid - off] : 0;
        __syncthreads();
        lofs[tid] += t;
        __syncthreads();
    }
    int excl = lofs[tid] - v;
    __syncthreads();
    lcnt[tid] = excl;
    __syncthreads();
    for (int i = tid; i < n; i += 512) {
        int e = bp[i];
        int pos = atomicAdd(&lcnt[(e >> 17) & 511], 1);
        csr[gbase + pos] = e & 0x1FFFF;
    }
}

// ---------------- W pre-convert: Wh (4x64x64 fp32) -> fragment-ordered fp16 ----------------
// Wf[layer][((ct*2+c)*64 + lane)*8 + j] = W[layer][c*32 + (lane>>4)*8 + j][ct*16 + (lane&15)]
__global__ __launch_bounds__(512) void wcvt_kernel(const float* __restrict__ Wh,
                                                   _Float16* __restrict__ Wf) {
    int t = blockIdx.x * blockDim.x + threadIdx.x;   // 2048 = 4 layers * 512
    if (t >= 4 * 512) return;
    int layer = t >> 9, rem = t & 511;
    int ct = rem >> 7, c = (rem >> 6) & 1, lane = rem & 63;
    const float* W = Wh + (size_t)layer * Cc * Cc;
    _Float16* o = Wf + (size_t)layer * 4096 + ((size_t)(ct * 2 + c) * 64 + lane) * 8;
    int kbase = c * 32 + (lane >> 4) * 8;
    int col = ct * 16 + (lane & 15);
    #pragma unroll
    for (int j = 0; j < 8; ++j) o[j] = (_Float16)W[(kbase + j) * 64 + col];
}

// ---------------- GEMM layer0 (fp32 x): T = fp16( dinv * (X @ W0) ) ----------------
__global__ __launch_bounds__(256) void gemm_xw_f32(const float* __restrict__ X,
                                                   const float* __restrict__ W,
                                                   const float* __restrict__ dinv,
                                                   __half* __restrict__ Y, int n) {
    __shared__ float hs[64][68];
    __shared__ float ws[64][64];
    const int tid = threadIdx.x;
    const int tx  = tid & 15;
    const int ty  = tid >> 4;
    const int rowbase = blockIdx.x * 64;

    float acc[4][4] = {};

    for (int k0 = 0; k0 < Ff; k0 += 64) {
        #pragma unroll
        for (int i = 0; i < 4; ++i) {
            int r = ty + i * 16;
            int gr = rowbase + r;
            float4 v = make_float4(0.f, 0.f, 0.f, 0.f);
            if (gr < n) v = *(const float4*)(X + (size_t)gr * Ff + k0 + tx * 4);
            *(float4*)&hs[r][tx * 4] = v;
        }
        #pragma unroll
        for (int i = 0; i < 4; ++i) {
            int k = ty + i * 16;
            *(float4*)&ws[k][tx * 4] = *(const float4*)(W + (size_t)(k0 + k) * 64 + tx * 4);
        }
        __syncthreads();

        #pragma unroll 4
        for (int k = 0; k < 64; ++k) {
            float4 w = *(const float4*)&ws[k][tx * 4];
            float h0 = hs[ty * 4 + 0][k];
            float h1 = hs[ty * 4 + 1][k];
            float h2 = hs[ty * 4 + 2][k];
            float h3 = hs[ty * 4 + 3][k];
            acc[0][0] += h0 * w.x; acc[0][1] += h0 * w.y; acc[0][2] += h0 * w.z; acc[0][3] += h0 * w.w;
            acc[1][0] += h1 * w.x; acc[1][1] += h1 * w.y; acc[1][2] += h1 * w.z; acc[1][3] += h1 * w.w;
            acc[2][0] += h2 * w.x; acc[2][1] += h2 * w.y; acc[2][2] += h2 * w.z; acc[2][3] += h2 * w.w;
            acc[3][0] += h3 * w.x; acc[3][1] += h3 * w.y; acc[3][2] += h3 * w.z; acc[3][3] += h3 * w.w;
        }
        __syncthreads();
    }

    #pragma unroll
    for (int i = 0; i < 4; ++i) {
        int gr = rowbase + ty * 4 + i;
        if (gr < n) {
            float di = dinv[gr];
            __half2 p0 = __floats2half2_rn(acc[i][0] * di, acc[i][1] * di);
            __half2 p1 = __floats2half2_rn(acc[i][2] * di, acc[i][3] * di);
            float2 st;
            *reinterpret_cast<__half2*>(&st.x) = p0;
            *reinterpret_cast<__half2*>(&st.y) = p1;
            *reinterpret_cast<float2*>(Y + (size_t)gr * 64 + tx * 4) = st;
        }
    }
}

// ---------------- hidden GEMM via MFMA: T = fp16( dinv * (H_f16 @ W) ) ----------------
// One wave per 16-node tile. A-frag: lane holds H[node0+(l&15)][c*32+(l>>4)*8 + 0..7].
// B-frag from fragment-ordered Wf (coalesced 16B). D: col=lane&15, row=(lane>>4)*4+reg.
__global__ __launch_bounds__(256) void gemm_mfma(const __half* __restrict__ A16,
                                                 const _Float16* __restrict__ Wf,
                                                 const float* __restrict__ dinv,
                                                 __half* __restrict__ Y, int n) {
    __shared__ _Float16 lds[4][1024];   // per-wave 16x64 tile
    const int tid  = threadIdx.x;
    const int lane = tid & 63;
    const int w    = tid >> 6;
    const int wid  = (blockIdx.x * 256 + tid) >> 6;
    const int ntiles = n >> 4;          // 6250
    if (wid >= ntiles) return;
    const int node0 = wid * 16;

    // B fragments: 4 cout-tiles x 2 K-chunks
    half8 bfrag[4][2];
    #pragma unroll
    for (int ct = 0; ct < 4; ++ct)
        #pragma unroll
        for (int c = 0; c < 2; ++c)
            bfrag[ct][c] = *(const half8*)(Wf + ((size_t)(ct * 2 + c) * 64 + lane) * 8);

    // A fragments: 2 K-chunks
    const _Float16* Ap = (const _Float16*)A16 + (size_t)(node0 + (lane & 15)) * 64 + (lane >> 4) * 8;
    half8 afrag0 = *(const half8*)(Ap);
    half8 afrag1 = *(const half8*)(Ap + 32);

    f32x4 acc[4] = {};
    #pragma unroll
    for (int ct = 0; ct < 4; ++ct) {
        acc[ct] = __builtin_amdgcn_mfma_f32_16x16x32_f16(afrag0, bfrag[ct][0], acc[ct], 0, 0, 0);
        acc[ct] = __builtin_amdgcn_mfma_f32_16x16x32_f16(afrag1, bfrag[ct][1], acc[ct], 0, 0, 0);
    }

    // dinv for my 4 rows
    const int r0 = (lane >> 4) * 4;
    float di[4];
    #pragma unroll
    for (int r = 0; r < 4; ++r) di[r] = dinv[node0 + r0 + r];

    // D -> LDS (row-major 16x64 fp16), per-wave slab, wave-local ordering only
    #pragma unroll
    for (int ct = 0; ct < 4; ++ct)
        #pragma unroll
        for (int r = 0; r < 4; ++r)
            lds[w][(r0 + r) * 64 + ct * 16 + (lane & 15)] = (_Float16)(acc[ct][r] * di[r]);

    asm volatile("s_waitcnt lgkmcnt(0)" ::: "memory");

    // coalesced store: 2 passes of 8 rows x 8 chunks of 16B
    #pragma unroll
    for (int p = 0; p < 2; ++p) {
        int row = p * 8 + (lane >> 3);
        int ch  = lane & 7;
        half8 v = *(const half8*)&lds[w][row * 64 + ch * 8];
        *(half8*)((_Float16*)Y + (size_t)(node0 + row) * 64 + ch * 8) = v;
    }
}

// ---------------- fp16 helpers ----------------
__device__ inline void add_h8(float acc[8], float4 raw) {
    const __half2* hp = reinterpret_cast<const __half2*>(&raw);
    #pragma unroll
    for (int j = 0; j < 4; ++j) {
        float2 f = __half22float2(hp[j]);
        acc[2 * j]     += f.x;
        acc[2 * j + 1] += f.y;
    }
}

__device__ inline void cvt_h8(float4 raw, float v[8]) {
    const __half2* hp = reinterpret_cast<const __half2*>(&raw);
    #pragma unroll
    for (int j = 0; j < 4; ++j) {
        float2 f = __half22float2(hp[j]);
        v[2 * j] = f.x; v[2 * j + 1] = f.y;
    }
}

// ---------------- CSR gather-aggregate over fp16 t' -> fp16 h ----------------
__global__ __launch_bounds__(256) void gather_agg(const int* __restrict__ row_off,
                                                  const int* __restrict__ csr_src,
                                                  const float* __restrict__ dinv,
                                                  const __half* __restrict__ t,
                                                  const float* __restrict__ b,
                                                  __half* __restrict__ out, int n) {
    const int lane = threadIdx.x & 63;
    const int node = (blockIdx.x * blockDim.x + threadIdx.x) >> 6;
    if (node >= n) return;
    const int sub = lane >> 3;
    const int c8  = lane & 7;

    const int base = row_off[node];
    const int end  = row_off[node + 1];

    float acc[8] = {};

    for (int k0 = base; k0 < end; k0 += 64) {
        int myidx = (k0 + lane < end) ? csr_src[k0 + lane] : 0;
        int nk = min(64, end - k0);
        int k = 0;
        for (; k + 16 <= nk; k += 16) {
            int s0 = __shfl(myidx, k + sub);
            int s1 = __shfl(myidx, k + 8 + sub);
            float4 r0 = *(const float4*)(t + (size_t)s0 * 64 + c8 * 8);
            float4 r1 = *(const float4*)(t + (size_t)s1 * 64 + c8 * 8);
            add_h8(acc, r0);
            add_h8(acc, r1);
        }
        for (; k < nk; k += 8) {
            int kk = k + sub;
            int s = __shfl(myidx, kk);
            if (kk < nk) {
                float4 r = *(const float4*)(t + (size_t)s * 64 + c8 * 8);
                add_h8(acc, r);
            }
        }
    }

    #pragma unroll
    for (int off = 8; off < 64; off <<= 1) {
        #pragma unroll
        for (int j = 0; j < 8; ++j) acc[j] += __shfl_xor(acc[j], off);
    }

    if (sub == 0) {
        float di = dinv[node];
        float selfv[8];
        cvt_h8(*(const float4*)(t + (size_t)node * 64 + c8 * 8), selfv);
        float4 b0 = *(const float4*)(b + c8 * 8);
        float4 b1 = *(const float4*)(b + c8 * 8 + 4);
        float bb[8] = {b0.x, b0.y, b0.z, b0.w, b1.x, b1.y, b1.z, b1.w};
        __half2 o[4];
        #pragma unroll
        for (int j = 0; j < 4; ++j) {
            float v0 = fmaxf(di * (acc[2 * j]     + selfv[2 * j])     + bb[2 * j],     0.f);
            float v1 = fmaxf(di * (acc[2 * j + 1] + selfv[2 * j + 1]) + bb[2 * j + 1], 0.f);
            o[j] = __floats2half2_rn(v0, v1);
        }
        *(float4*)(out + (size_t)node * 64 + c8 * 8) = *reinterpret_cast<float4*>(o);
    }
}

// ---------------- pooling via sorted-batch segments ----------------
__global__ __launch_bounds__(256) void pool_graph(const __half* __restrict__ h,
                                                  const int* __restrict__ gstart,
                                                  float* __restrict__ pooled) {
    __shared__ float sd[4][64];
    const int g    = blockIdx.x;
    const int lane = threadIdx.x & 63;
    const int wv   = threadIdx.x >> 6;
    const int s = gstart[g], e = gstart[g + 1];
    float acc = 0.f;
    for (int i = s + wv; i < e; i += 4) acc += __half2float(h[(size_t)i * 64 + lane]);
    sd[wv][lane] = acc;
    __syncthreads();
    if (wv == 0) {
        float sum = sd[0][lane] + sd[1][lane] + sd[2][lane] + sd[3][lane];
        float c = (float)(e - s);
        pooled[(size_t)g * 64 + lane] = sum / fmaxf(c, 1.f);
    }
}

// ---------------- MLP head ----------------
__global__ void mlp1_kernel(const float* __restrict__ P, const float* __restrict__ W1,
                            const float* __restrict__ b1, float* __restrict__ H) {
    int gid = blockIdx.x * blockDim.x + threadIdx.x;
    if (gid >= Gg * NHh) return;
    int j = gid & (NHh - 1), g = gid >> 8;
    const float* p = P + (size_t)g * Cc;
    float s = b1[j];
    #pragma unroll 8
    for (int k = 0; k < Cc; ++k) s += p[k] * W1[(size_t)k * NHh + j];
    H[gid] = fmaxf(s, 0.f);
}

__global__ void mlp2_kernel(const float* __restrict__ H, const float* __restrict__ W2,
                            const float* __restrict__ b2, float* __restrict__ O) {
    int gid = blockIdx.x * blockDim.x + threadIdx.x;
    if (gid >= Gg * NOUTt) return;
    int j = gid & (NOUTt - 1), g = gid >> 7;
    const float* h = H + (size_t)g * NHh;
    float s = b2[j];
    #pragma unroll 8
    for (int k = 0; k < NHh; ++k) s += h[k] * W2[(size_t)k * NOUTt + j];
    O[gid] = s;
}

// ---------------- launch ----------------
extern "C" void kernel_launch(void* const* d_in, const int* in_sizes, int n_in,
                              void* d_out, int out_size, void* d_ws, size_t ws_size,
                              hipStream_t stream) {
    const float* x     = (const float*)d_in[0];
    const int*   ei    = (const int*)  d_in[1];
    const int*   batch = (const int*)  d_in[2];
    const float* W0    = (const float*)d_in[3];
    const float* b0    = (const float*)d_in[4];
    const float* Wh    = (const float*)d_in[5];
    const float* bh    = (const float*)d_in[6];
    const float* W1    = (const float*)d_in[7];
    const float* b1    = (const float*)d_in[8];
    const float* W2    = (const float*)d_in[9];
    const float* b2    = (const float*)d_in[10];

    const int* src = ei;
    const int* dst = ei + Ee;

    char* ws = (char*)d_ws;
    constexpr size_t OFF_DINV  = 0;
    constexpr size_t OFF_CNT   = 400384;
    constexpr size_t OFF_ROFF  = OFF_CNT + 400384;
    constexpr size_t OFF_BSUM  = OFF_ROFF + 400384;
    constexpr size_t OFF_BOFF  = OFF_BSUM + 1024;
    constexpr size_t OFF_SCNT  = OFF_BOFF + 1024;
    constexpr size_t OFF_CSR   = OFF_SCNT + 1024;
    constexpr size_t OFF_T     = OFF_CSR + 6400256;               // fp16 t' 12.8MB
    constexpr size_t OFF_A     = OFF_T + 12800256;                // fp16 h 12.8MB
    constexpr size_t OFF_POOL  = OFF_A + 12800256;
    constexpr size_t OFF_GST   = OFF_POOL + (size_t)Gg * Cc * 4;
    constexpr size_t OFF_HID   = OFF_GST + 4096;
    constexpr size_t OFF_WF    = OFF_HID + (size_t)Gg * NHh * 4;  // 32KB frag-ordered Wh
    const size_t OFF_SB = OFF_T;   // sub-buckets (8.03MB) alias T (dead until gemm)

    float*    dinv   = (float*)   (ws + OFF_DINV);
    int*      cnt    = (int*)     (ws + OFF_CNT);
    int*      roff   = (int*)     (ws + OFF_ROFF);
    int*      bsum   = (int*)     (ws + OFF_BSUM);
    int*      boff   = (int*)     (ws + OFF_BOFF);
    int*      scnt   = (int*)     (ws + OFF_SCNT);
    int*      csrs   = (int*)     (ws + OFF_CSR);
    int*      sb     = (int*)     (ws + OFF_SB);
    __half*   T      = (__half*)  (ws + OFF_T);
    __half*   A      = (__half*)  (ws + OFF_A);
    float*    pooled = (float*)   (ws + OFF_POOL);
    int*      gstart = (int*)     (ws + OFF_GST);
    float*    hid    = (float*)   (ws + OFF_HID);
    _Float16* Wf     = (_Float16*)(ws + OFF_WF);

    // ---- CSR build + W pre-convert ----
    hipMemsetAsync(scnt, 0, 1024, stream);
    wcvt_kernel<<<4, 512, 0, stream>>>(Wh, Wf);
    bin_kernel<<<(Ee + 2047) / 2048, 256, 0, stream>>>(src, dst, sb, scnt, Ee);
    cnt3_kernel<<<NSUB, 512, 0, stream>>>(sb, scnt, cnt, dinv);
    scan1_kernel<<<NBLK_SCAN, SCAN_BLK, 0, stream>>>(cnt, roff, bsum, Nn);
    scan2_kernel<<<1, 128, 0, stream>>>(bsum, boff, NBLK_SCAN);
    scan3_kernel<<<(Nn + 255) / 256, 256, 0, stream>>>(roff, boff, batch, gstart, Nn);
    fill3_kernel<<<NSUB, 512, 0, stream>>>(sb, scnt, roff, csrs);

    const int gemm_blocks = (Nn + 63) / 64;
    const int agg_blocks  = (Nn * 64 + 255) / 256;
    const int mfma_blocks = ((Nn / 16) + 3) / 4;   // 1563 (4 waves/block, 1 tile/wave)

    // ---- layer 0: x @ W0 (dinv-scaled, fp16) -> gather -> h(fp16) in A ----
    gemm_xw_f32<<<gemm_blocks, 256, 0, stream>>>(x, W0, dinv, T, Nn);
    gather_agg<<<agg_blocks, 256, 0, stream>>>(roff, csrs, dinv, T, b0, A, Nn);

    // ---- hidden layers: MFMA gemm(A -> T), gather(T -> A) ----
    for (int i = 0; i < Ll; ++i) {
        gemm_mfma<<<mfma_blocks, 256, 0, stream>>>(A, Wf + (size_t)i * 4096, dinv, T, Nn);
        gather_agg<<<agg_blocks, 256, 0, stream>>>(roff, csrs, dinv, T, bh + (size_t)i * Cc, A, Nn);
    }

    // ---- global mean pool ----
    pool_graph<<<Gg, 256, 0, stream>>>(A, gstart, pooled);

    // ---- MLP head ----
    mlp1_kernel<<<(Gg * NHh + 255) / 256, 256, 0, stream>>>(pooled, W1, b1, hid);
    mlp2_kernel<<<(Gg * NOUTt + 255) / 256, 256, 0, stream>>>(hid, W2, b2, (float*)d_out);
}